// Round 7
// baseline (1123.275 us; speedup 1.0000x reference)
//
#include <hip/hip_runtime.h>
#include <hip/hip_fp16.h>

#define NBUK   1563         // ceil(100000 / 64) buckets of 64 dst nodes
#define CHUNK  3072         // edges per scatter block (512 threads x 6)
#define NSLICE 4            // src slices of 32768 nodes (2.56MB fp16 rows < 4MB L2/XCD)

// Workspace layout (bytes). g is now fp16 (8 MB); offsets kept from prior rounds.
#define WS_FLAG   0u
#define WS_GCNT   1024u      // 1563*4 = 6252
#define WS_GSTART 8192u
#define WS_GCUR   16384u
#define WS_DINV   24576u     // 400000 B
#define WS_G      425984u    // 8,000,000 B (fp16)
#define WS_BUCK   16425984u  // 12,800,000 B -> ends 29,225,984

// Detect whether edge_index arrived as int64 (odd int32 words all zero) or int32.
static __global__ void k_detect(const int* __restrict__ ei, int* __restrict__ flag) {
    if (blockIdx.x == 0 && threadIdx.x == 0) {
        int allz = 1;
        for (int t = 1; t < 256; t += 2) {
            if (ei[t] != 0) { allz = 0; break; }
        }
        *flag = allz;
    }
}

// Per-bucket edge counts via LDS histogram (dst bucket = dst >> 6).
static __global__ __launch_bounds__(512) void k_bcount(const int* __restrict__ ei, int E,
                                                       const int* __restrict__ flag,
                                                       int* __restrict__ gcnt) {
    __shared__ int h[NBUK];
    const int t = threadIdx.x;
    for (int b = t; b < NBUK; b += 512) h[b] = 0;
    __syncthreads();
    const int is64 = *flag;
    const int i0 = blockIdx.x * CHUNK;
    const int i1 = min(E, i0 + CHUNK);
    if (is64) {
        for (int e = i0 + t; e < i1; e += 512) atomicAdd(&h[ei[2 * (E + e)] >> 6], 1);
    } else {
        for (int e = i0 + t; e < i1; e += 512) atomicAdd(&h[ei[E + e] >> 6], 1);
    }
    __syncthreads();
    for (int b = t; b < NBUK; b += 512)
        if (h[b]) atomicAdd(&gcnt[b], h[b]);
}

// Exclusive scan of the 1563 bucket counts; gstart = offsets, gcur = working copy.
// 512 threads, 4 buckets per thread.
static __global__ __launch_bounds__(512) void k_bscan(const int* __restrict__ gcnt,
                                                      int* __restrict__ gstart,
                                                      int* __restrict__ gcur) {
    __shared__ int sc[512];
    const int t = threadIdx.x;
    int vloc[4];
    int s = 0;
#pragma unroll
    for (int i = 0; i < 4; ++i) {
        const int idx = 4 * t + i;
        vloc[i] = (idx < NBUK) ? gcnt[idx] : 0;
        s += vloc[i];
    }
    sc[t] = s;
    __syncthreads();
    for (int st = 1; st < 512; st <<= 1) {
        const int a = (t >= st) ? sc[t - st] : 0;
        __syncthreads();
        sc[t] += a;
        __syncthreads();
    }
    int run = sc[t] - s;  // exclusive prefix of this thread's group
#pragma unroll
    for (int i = 0; i < 4; ++i) {
        const int idx = 4 * t + i;
        if (idx < NBUK) { gstart[idx] = run; gcur[idx] = run; }
        run += vloc[i];
    }
}

// Bucket-sort each block's 3072 edges in LDS, reserve per-bucket global ranges,
// write payloads (src | dst_local<<17) with lane-consecutive addresses.
static __global__ __launch_bounds__(512) void k_scatter(const int* __restrict__ ei, int E,
                                                        const int* __restrict__ flag,
                                                        int* __restrict__ gcur,
                                                        unsigned* __restrict__ buck) {
    __shared__ int hist[NBUK];
    __shared__ int lofs[NBUK];
    __shared__ int base[NBUK];
    __shared__ int cur[NBUK];
    __shared__ int sc[512];
    __shared__ unsigned stag[CHUNK];
    __shared__ unsigned short bkt[CHUNK];

    const int t = threadIdx.x;
    const int is64 = *flag;
    const int i0 = blockIdx.x * CHUNK;
    const int i1 = min(E, i0 + CHUNK);
    const int nloc = i1 - i0;

    for (int b = t; b < NBUK; b += 512) hist[b] = 0;
    __syncthreads();

    // Pass A: local histogram.
    if (is64) {
        for (int e = i0 + t; e < i1; e += 512) atomicAdd(&hist[ei[2 * (E + e)] >> 6], 1);
    } else {
        for (int e = i0 + t; e < i1; e += 512) atomicAdd(&hist[ei[E + e] >> 6], 1);
    }
    __syncthreads();

    // Exclusive scan of hist -> lofs (4 buckets per thread).
    int vloc[4];
    int s = 0;
#pragma unroll
    for (int i = 0; i < 4; ++i) {
        const int idx = 4 * t + i;
        vloc[i] = (idx < NBUK) ? hist[idx] : 0;
        s += vloc[i];
    }
    sc[t] = s;
    __syncthreads();
    for (int st = 1; st < 512; st <<= 1) {
        const int a = (t >= st) ? sc[t - st] : 0;
        __syncthreads();
        sc[t] += a;
        __syncthreads();
    }
    int run = sc[t] - s;
#pragma unroll
    for (int i = 0; i < 4; ++i) {
        const int idx = 4 * t + i;
        if (idx < NBUK) lofs[idx] = run;
        run += vloc[i];
    }
    for (int b = t; b < NBUK; b += 512) {
        const int h = hist[b];
        base[b] = h ? atomicAdd(&gcur[b], h) : 0;
        cur[b]  = 0;
    }
    __syncthreads();

    // Pass B: place edges into LDS staging, sorted by bucket.
    if (is64) {
        for (int e = i0 + t; e < i1; e += 512) {
            const int s2 = ei[2 * e];
            const int d  = ei[2 * (E + e)];
            const int b  = d >> 6;
            const int l  = atomicAdd(&cur[b], 1);
            const int p  = lofs[b] + l;
            stag[p] = (unsigned)s2 | ((unsigned)(d & 63) << 17);
            bkt[p]  = (unsigned short)b;
        }
    } else {
        for (int e = i0 + t; e < i1; e += 512) {
            const int s2 = ei[e];
            const int d  = ei[E + e];
            const int b  = d >> 6;
            const int l  = atomicAdd(&cur[b], 1);
            const int p  = lofs[b] + l;
            stag[p] = (unsigned)s2 | ((unsigned)(d & 63) << 17);
            bkt[p]  = (unsigned short)b;
        }
    }
    __syncthreads();

    // Pass C: write out; consecutive j within a bucket run -> consecutive global addrs.
    for (int j = t; j < nloc; j += 512) {
        const int b = bkt[j];
        buck[(size_t)base[b] + (j - lofs[b])] = stag[j];
    }
}

// Per-bucket degree histogram -> dinv (deg includes +1 self-loop).
static __global__ __launch_bounds__(256) void k_bdeg(const unsigned* __restrict__ buck,
                                                     const int* __restrict__ gstart,
                                                     const int* __restrict__ gcnt,
                                                     float* __restrict__ dinv, int N) {
    __shared__ int h[64];
    const int b = blockIdx.x, t = threadIdx.x;
    if (t < 64) h[t] = 0;
    __syncthreads();
    const int s0 = gstart[b], n = gcnt[b];
    for (int j = t; j < n; j += 256) atomicAdd(&h[buck[s0 + j] >> 17], 1);
    __syncthreads();
    const int node = b * 64 + t;
    if (t < 64 && node < N) dinv[node] = rsqrtf((float)(h[t] + 1));
}

// g[i][c] = fp16( (x[i,:] @ W[:,c]) * dinv[i] ).  Thread-per-row, 40 f32 accumulators.
static __global__ __launch_bounds__(256) void k_h(const float* __restrict__ x,
                                                  const float* __restrict__ W,
                                                  const float* __restrict__ dinv,
                                                  __half* __restrict__ g, int n) {
    const int row = blockIdx.x * 256 + threadIdx.x;
    if (row >= n) return;
    float acc[40];
#pragma unroll
    for (int c = 0; c < 40; ++c) acc[c] = 0.f;
    const float* xr = x + (size_t)row * 512;
    for (int k = 0; k < 512; k += 4) {
        const float4 xv = *reinterpret_cast<const float4*>(xr + k);
        const float xs[4] = {xv.x, xv.y, xv.z, xv.w};
#pragma unroll
        for (int j = 0; j < 4; ++j) {
            const float* wr = W + (size_t)(k + j) * 40;
#pragma unroll
            for (int c = 0; c < 40; ++c) acc[c] = fmaf(xs[j], wr[c], acc[c]);
        }
    }
    const float dv = dinv[row];
    __half2* gr = reinterpret_cast<__half2*>(g + (size_t)row * 40);
#pragma unroll
    for (int c = 0; c < 40; c += 2)
        gr[c >> 1] = __floats2half2_rn(acc[c] * dv, acc[c + 1] * dv);
}

// Fused gather + bias + log_softmax. One block per 64-node bucket.
// One edge per wave-step, lanes 0..39 = features (coalesced 80B fp16 row read).
// 4 src-slice passes: pass s touches only rows in a 2.56MB slice -> per-XCD L2 resident.
static __global__ __launch_bounds__(256) void k_gather(const __half* __restrict__ g,
                                                       const unsigned* __restrict__ buck,
                                                       const int* __restrict__ gstart,
                                                       const int* __restrict__ gcnt,
                                                       const float* __restrict__ dinv,
                                                       const float* __restrict__ bias,
                                                       float* __restrict__ out, int N) {
    __shared__ float acc[64][41];  // stride 41: conflict-free for both patterns
    const int b = blockIdx.x, t = threadIdx.x;
    const int nbase = b * 64;
    const int nloc = min(64, N - nbase);
    const int wid = t >> 6, lane = t & 63;

    // Init with self-loop term g[i] (dinv[i] already folded into g).
    for (int idx = t; idx < nloc * 40; idx += 256) {
        const int r = idx / 40, c = idx - r * 40;
        acc[r][c] = __half2float(g[(size_t)(nbase + r) * 40 + c]);
    }
    __syncthreads();

    // Each wave owns a contiguous quarter of the bucket's edge list; walk it
    // NSLICE times, processing only edges whose src lies in the current slice.
    const int s0 = gstart[b], n = gcnt[b];
    const int n4 = (n + 3) >> 2;
    const int jb = s0 + wid * n4;
    const int je = s0 + min(n, (wid + 1) * n4);

    if (lane < 40) {
        for (int sl = 0; sl < NSLICE; ++sl) {
            for (int j = jb; j < je; ++j) {
                const unsigned p = buck[j];            // wave-uniform broadcast
                const int src = (int)(p & 0x1FFFFu);
                if ((src >> 15) != sl) continue;       // wave-uniform skip
                const float v = __half2float(g[(size_t)src * 40 + lane]);
                atomicAdd(&acc[p >> 17][lane], v);
            }
        }
    }
    __syncthreads();

    // Epilogue: scale by dinv[dst], add bias, log_softmax, store.
    if (t < nloc) {
        const int node = nbase + t;
        const float dv = dinv[node];
        float v[40];
        float m = -1e30f;
#pragma unroll
        for (int c = 0; c < 40; ++c) {
            v[c] = acc[t][c] * dv + bias[c];
            m = fmaxf(m, v[c]);
        }
        float s = 0.f;
#pragma unroll
        for (int c = 0; c < 40; ++c) s += __expf(v[c] - m);
        const float l = m + __logf(s);
        float* r = out + (size_t)node * 40;
#pragma unroll
        for (int c = 0; c < 40; c += 4) {
            float4 o;
            o.x = v[c + 0] - l;
            o.y = v[c + 1] - l;
            o.z = v[c + 2] - l;
            o.w = v[c + 3] - l;
            *reinterpret_cast<float4*>(r + c) = o;
        }
    }
}

extern "C" void kernel_launch(void* const* d_in, const int* in_sizes, int n_in,
                              void* d_out, int out_size, void* d_ws, size_t ws_size,
                              hipStream_t stream) {
    const float* x  = (const float*)d_in[0];
    const int*   ei = (const int*)d_in[1];
    const float* W  = (const float*)d_in[2];
    const float* b  = (const float*)d_in[3];
    float* out = (float*)d_out;

    const int N = in_sizes[0] / 512;  // 100000
    const int E = in_sizes[1] / 2;    // 3200000

    char* ws = (char*)d_ws;
    int*      flag   = (int*)(ws + WS_FLAG);
    int*      gcnt   = (int*)(ws + WS_GCNT);
    int*      gstart = (int*)(ws + WS_GSTART);
    int*      gcur   = (int*)(ws + WS_GCUR);
    float*    dinv   = (float*)(ws + WS_DINV);
    __half*   g      = (__half*)(ws + WS_G);
    unsigned* buck   = (unsigned*)(ws + WS_BUCK);

    const int NBH  = (N + 255) / 256;          // 391 blocks for k_h
    const int NEB  = (E + CHUNK - 1) / CHUNK;  // 1042

    hipMemsetAsync(gcnt, 0, NBUK * sizeof(int), stream);
    k_detect<<<1, 64, 0, stream>>>(ei, flag);
    k_bcount<<<NEB, 512, 0, stream>>>(ei, E, flag, gcnt);
    k_bscan<<<1, 512, 0, stream>>>(gcnt, gstart, gcur);
    k_scatter<<<NEB, 512, 0, stream>>>(ei, E, flag, gcur, buck);
    k_bdeg<<<NBUK, 256, 0, stream>>>(buck, gstart, gcnt, dinv, N);
    k_h<<<NBH, 256, 0, stream>>>(x, W, dinv, g, N);
    k_gather<<<NBUK, 256, 0, stream>>>(g, buck, gstart, gcnt, dinv, b, out, N);
}

// Round 8
// 967.832 us; speedup vs baseline: 1.1606x; 1.1606x over previous
//
#include <hip/hip_runtime.h>
#include <hip/hip_fp16.h>

#define NBUK   1563         // ceil(100000 / 64) buckets of 64 dst nodes
#define CHUNK  3072         // edges per scatter block (512 threads x 6)
#define PCAP   3072         // LDS payload staging capacity per bucket

// Workspace layout (bytes).
#define WS_FLAG   0u
#define WS_GCNT   1024u      // 1563*4 = 6252
#define WS_GSTART 8192u
#define WS_GCUR   16384u
#define WS_DINV   24576u     // 400000 B
#define WS_G      425984u    // plane0: 4,000,000 B (fp16, classes 0..19)
#define WS_G2     4425984u   // plane1: 4,000,000 B (fp16, classes 20..39)
#define WS_BUCK   16425984u  // 12,800,000 B -> ends 29,225,984

// Detect whether edge_index arrived as int64 (odd int32 words all zero) or int32.
static __global__ void k_detect(const int* __restrict__ ei, int* __restrict__ flag) {
    if (blockIdx.x == 0 && threadIdx.x == 0) {
        int allz = 1;
        for (int t = 1; t < 256; t += 2) {
            if (ei[t] != 0) { allz = 0; break; }
        }
        *flag = allz;
    }
}

// Per-bucket edge counts via LDS histogram (dst bucket = dst >> 6).
static __global__ __launch_bounds__(512) void k_bcount(const int* __restrict__ ei, int E,
                                                       const int* __restrict__ flag,
                                                       int* __restrict__ gcnt) {
    __shared__ int h[NBUK];
    const int t = threadIdx.x;
    for (int b = t; b < NBUK; b += 512) h[b] = 0;
    __syncthreads();
    const int is64 = *flag;
    const int i0 = blockIdx.x * CHUNK;
    const int i1 = min(E, i0 + CHUNK);
    if (is64) {
        for (int e = i0 + t; e < i1; e += 512) atomicAdd(&h[ei[2 * (E + e)] >> 6], 1);
    } else {
        for (int e = i0 + t; e < i1; e += 512) atomicAdd(&h[ei[E + e] >> 6], 1);
    }
    __syncthreads();
    for (int b = t; b < NBUK; b += 512)
        if (h[b]) atomicAdd(&gcnt[b], h[b]);
}

// Exclusive scan of the 1563 bucket counts; gstart = offsets, gcur = working copy.
static __global__ __launch_bounds__(512) void k_bscan(const int* __restrict__ gcnt,
                                                      int* __restrict__ gstart,
                                                      int* __restrict__ gcur) {
    __shared__ int sc[512];
    const int t = threadIdx.x;
    int vloc[4];
    int s = 0;
#pragma unroll
    for (int i = 0; i < 4; ++i) {
        const int idx = 4 * t + i;
        vloc[i] = (idx < NBUK) ? gcnt[idx] : 0;
        s += vloc[i];
    }
    sc[t] = s;
    __syncthreads();
    for (int st = 1; st < 512; st <<= 1) {
        const int a = (t >= st) ? sc[t - st] : 0;
        __syncthreads();
        sc[t] += a;
        __syncthreads();
    }
    int run = sc[t] - s;  // exclusive prefix of this thread's group
#pragma unroll
    for (int i = 0; i < 4; ++i) {
        const int idx = 4 * t + i;
        if (idx < NBUK) { gstart[idx] = run; gcur[idx] = run; }
        run += vloc[i];
    }
}

// Bucket-sort each block's 3072 edges in LDS, reserve per-bucket global ranges,
// write payloads (src | dst_local<<17) with lane-consecutive addresses.
static __global__ __launch_bounds__(512) void k_scatter(const int* __restrict__ ei, int E,
                                                        const int* __restrict__ flag,
                                                        int* __restrict__ gcur,
                                                        unsigned* __restrict__ buck) {
    __shared__ int hist[NBUK];
    __shared__ int lofs[NBUK];
    __shared__ int base[NBUK];
    __shared__ int cur[NBUK];
    __shared__ int sc[512];
    __shared__ unsigned stag[CHUNK];
    __shared__ unsigned short bkt[CHUNK];

    const int t = threadIdx.x;
    const int is64 = *flag;
    const int i0 = blockIdx.x * CHUNK;
    const int i1 = min(E, i0 + CHUNK);
    const int nloc = i1 - i0;

    for (int b = t; b < NBUK; b += 512) hist[b] = 0;
    __syncthreads();

    // Pass A: local histogram.
    if (is64) {
        for (int e = i0 + t; e < i1; e += 512) atomicAdd(&hist[ei[2 * (E + e)] >> 6], 1);
    } else {
        for (int e = i0 + t; e < i1; e += 512) atomicAdd(&hist[ei[E + e] >> 6], 1);
    }
    __syncthreads();

    // Exclusive scan of hist -> lofs (4 buckets per thread).
    int vloc[4];
    int s = 0;
#pragma unroll
    for (int i = 0; i < 4; ++i) {
        const int idx = 4 * t + i;
        vloc[i] = (idx < NBUK) ? hist[idx] : 0;
        s += vloc[i];
    }
    sc[t] = s;
    __syncthreads();
    for (int st = 1; st < 512; st <<= 1) {
        const int a = (t >= st) ? sc[t - st] : 0;
        __syncthreads();
        sc[t] += a;
        __syncthreads();
    }
    int run = sc[t] - s;
#pragma unroll
    for (int i = 0; i < 4; ++i) {
        const int idx = 4 * t + i;
        if (idx < NBUK) lofs[idx] = run;
        run += vloc[i];
    }
    for (int b = t; b < NBUK; b += 512) {
        const int h = hist[b];
        base[b] = h ? atomicAdd(&gcur[b], h) : 0;
        cur[b]  = 0;
    }
    __syncthreads();

    // Pass B: place edges into LDS staging, sorted by bucket.
    if (is64) {
        for (int e = i0 + t; e < i1; e += 512) {
            const int s2 = ei[2 * e];
            const int d  = ei[2 * (E + e)];
            const int b  = d >> 6;
            const int l  = atomicAdd(&cur[b], 1);
            const int p  = lofs[b] + l;
            stag[p] = (unsigned)s2 | ((unsigned)(d & 63) << 17);
            bkt[p]  = (unsigned short)b;
        }
    } else {
        for (int e = i0 + t; e < i1; e += 512) {
            const int s2 = ei[e];
            const int d  = ei[E + e];
            const int b  = d >> 6;
            const int l  = atomicAdd(&cur[b], 1);
            const int p  = lofs[b] + l;
            stag[p] = (unsigned)s2 | ((unsigned)(d & 63) << 17);
            bkt[p]  = (unsigned short)b;
        }
    }
    __syncthreads();

    // Pass C: write out; consecutive j within a bucket run -> consecutive global addrs.
    for (int j = t; j < nloc; j += 512) {
        const int b = bkt[j];
        buck[(size_t)base[b] + (j - lofs[b])] = stag[j];
    }
}

// Per-bucket degree histogram -> dinv (deg includes +1 self-loop).
static __global__ __launch_bounds__(256) void k_bdeg(const unsigned* __restrict__ buck,
                                                     const int* __restrict__ gstart,
                                                     const int* __restrict__ gcnt,
                                                     float* __restrict__ dinv, int N) {
    __shared__ int h[64];
    const int b = blockIdx.x, t = threadIdx.x;
    if (t < 64) h[t] = 0;
    __syncthreads();
    const int s0 = gstart[b], n = gcnt[b];
    for (int j = t; j < n; j += 256) atomicAdd(&h[buck[s0 + j] >> 17], 1);
    __syncthreads();
    const int node = b * 64 + t;
    if (t < 64 && node < N) dinv[node] = rsqrtf((float)(h[t] + 1));
}

// h = (x @ W) * dinv, written as TWO fp16 planes of 20 classes each
// (plane = 100K x 10 dwords = 4MB -> per-XCD-L2 resident during gather passes).
static __global__ __launch_bounds__(256) void k_h(const float* __restrict__ x,
                                                  const float* __restrict__ W,
                                                  const float* __restrict__ dinv,
                                                  unsigned* __restrict__ plane0,
                                                  unsigned* __restrict__ plane1, int n) {
    const int row = blockIdx.x * 256 + threadIdx.x;
    if (row >= n) return;
    float acc[40];
#pragma unroll
    for (int c = 0; c < 40; ++c) acc[c] = 0.f;
    const float* xr = x + (size_t)row * 512;
    for (int k = 0; k < 512; k += 4) {
        const float4 xv = *reinterpret_cast<const float4*>(xr + k);
        const float xs[4] = {xv.x, xv.y, xv.z, xv.w};
#pragma unroll
        for (int j = 0; j < 4; ++j) {
            const float* wr = W + (size_t)(k + j) * 40;
#pragma unroll
            for (int c = 0; c < 40; ++c) acc[c] = fmaf(xs[j], wr[c], acc[c]);
        }
    }
    const float dv = dinv[row];
    unsigned* p0 = plane0 + (size_t)row * 10;
    unsigned* p1 = plane1 + (size_t)row * 10;
#pragma unroll
    for (int d = 0; d < 10; ++d) {
        const __half2 h0 = __floats2half2_rn(acc[2 * d] * dv, acc[2 * d + 1] * dv);
        const __half2 h1 = __floats2half2_rn(acc[20 + 2 * d] * dv, acc[21 + 2 * d] * dv);
        p0[d] = *reinterpret_cast<const unsigned*>(&h0);
        p1[d] = *reinterpret_cast<const unsigned*>(&h1);
    }
}

// Fused gather + bias + log_softmax. One block per 64-node bucket.
// Payloads staged ONCE in LDS; two feature-plane passes (4MB working set each,
// per-XCD L2 resident); 6 edges per wave-load (lane = edge*10 + dword).
static __global__ __launch_bounds__(256) void k_gather(const unsigned* __restrict__ plane0,
                                                       const unsigned* __restrict__ plane1,
                                                       const unsigned* __restrict__ buck,
                                                       const int* __restrict__ gstart,
                                                       const int* __restrict__ gcnt,
                                                       const float* __restrict__ dinv,
                                                       const float* __restrict__ bias,
                                                       float* __restrict__ out, int N) {
    __shared__ float acc[64][41];   // stride 41: conflict-tame for random-row atomics
    __shared__ unsigned pay[PCAP];
    const int b = blockIdx.x, t = threadIdx.x;
    const int nbase = b * 64;
    const int nloc = min(64, N - nbase);
    const int wid = t >> 6, lane = t & 63;
    const int eo = lane / 10;            // edge slot 0..5 (lanes 60..63 idle)
    const int d  = lane - eo * 10;       // dword-in-row 0..9
    const bool act = lane < 60;

    const int s0 = gstart[b], n = gcnt[b];

    // Stage payloads (once; reused by both passes).
    const int nst = min(n, PCAP);
    for (int idx = t; idx < nst; idx += 256) pay[idx] = buck[s0 + idx];

    // Init acc with self-loop term from the planes (dinv[i] already folded in).
    for (int idx = t; idx < nloc * 20; idx += 256) {
        const int r = idx / 20, q = idx - r * 20;
        const unsigned u = (q < 10 ? plane0 : plane1)[(size_t)(nbase + r) * 10 + (q % 10)];
        const __half2 h = *reinterpret_cast<const __half2*>(&u);
        const int cb = (q < 10 ? 0 : 20) + (q % 10) * 2;
        acc[r][cb]     = __low2float(h);
        acc[r][cb + 1] = __high2float(h);
    }
    __syncthreads();

    // Each wave owns a contiguous quarter of the bucket's edge list (local idx).
    const int n4 = (n + 3) >> 2;
    const int jb = wid * n4;
    const int je = min(n, (wid + 1) * n4);

    for (int p = 0; p < 2; ++p) {
        const unsigned* __restrict__ pl = p ? plane1 : plane0;
        const int cb = p * 20 + d * 2;
        for (int j = jb; j < je; j += 6) {
            const int jl = j + eo;
            if (act && jl < je) {
                unsigned pv;
                if (jl < PCAP) pv = pay[jl]; else pv = buck[s0 + jl];  // rare fallback
                const unsigned src = pv & 0x1FFFFu;
                const int dl = (int)(pv >> 17);
                const unsigned u = pl[(size_t)src * 10 + d];   // 6 x 40B spans per wave
                const __half2 h = *reinterpret_cast<const __half2*>(&u);
                atomicAdd(&acc[dl][cb],     __low2float(h));
                atomicAdd(&acc[dl][cb + 1], __high2float(h));
            }
        }
    }
    __syncthreads();

    // Epilogue: scale by dinv[dst], add bias, log_softmax, store.
    if (t < nloc) {
        const int node = nbase + t;
        const float dv = dinv[node];
        float v[40];
        float m = -1e30f;
#pragma unroll
        for (int c = 0; c < 40; ++c) {
            v[c] = acc[t][c] * dv + bias[c];
            m = fmaxf(m, v[c]);
        }
        float s = 0.f;
#pragma unroll
        for (int c = 0; c < 40; ++c) s += __expf(v[c] - m);
        const float l = m + __logf(s);
        float* r = out + (size_t)node * 40;
#pragma unroll
        for (int c = 0; c < 40; c += 4) {
            float4 o;
            o.x = v[c + 0] - l;
            o.y = v[c + 1] - l;
            o.z = v[c + 2] - l;
            o.w = v[c + 3] - l;
            *reinterpret_cast<float4*>(r + c) = o;
        }
    }
}

extern "C" void kernel_launch(void* const* d_in, const int* in_sizes, int n_in,
                              void* d_out, int out_size, void* d_ws, size_t ws_size,
                              hipStream_t stream) {
    const float* x  = (const float*)d_in[0];
    const int*   ei = (const int*)d_in[1];
    const float* W  = (const float*)d_in[2];
    const float* b  = (const float*)d_in[3];
    float* out = (float*)d_out;

    const int N = in_sizes[0] / 512;  // 100000
    const int E = in_sizes[1] / 2;    // 3200000

    char* ws = (char*)d_ws;
    int*      flag   = (int*)(ws + WS_FLAG);
    int*      gcnt   = (int*)(ws + WS_GCNT);
    int*      gstart = (int*)(ws + WS_GSTART);
    int*      gcur   = (int*)(ws + WS_GCUR);
    float*    dinv   = (float*)(ws + WS_DINV);
    unsigned* plane0 = (unsigned*)(ws + WS_G);
    unsigned* plane1 = (unsigned*)(ws + WS_G2);
    unsigned* buck   = (unsigned*)(ws + WS_BUCK);

    const int NBH  = (N + 255) / 256;          // 391 blocks for k_h
    const int NEB  = (E + CHUNK - 1) / CHUNK;  // 1042

    hipMemsetAsync(gcnt, 0, NBUK * sizeof(int), stream);
    k_detect<<<1, 64, 0, stream>>>(ei, flag);
    k_bcount<<<NEB, 512, 0, stream>>>(ei, E, flag, gcnt);
    k_bscan<<<1, 512, 0, stream>>>(gcnt, gstart, gcur);
    k_scatter<<<NEB, 512, 0, stream>>>(ei, E, flag, gcur, buck);
    k_bdeg<<<NBUK, 256, 0, stream>>>(buck, gstart, gcnt, dinv, N);
    k_h<<<NBH, 256, 0, stream>>>(x, W, dinv, plane0, plane1, N);
    k_gather<<<NBUK, 256, 0, stream>>>(plane0, plane1, buck, gstart, gcnt, dinv, b, out, N);
}